// Round 14
// baseline (245.764 us; speedup 1.0000x reference)
//
#include <hip/hip_runtime.h>
#include <hip/hip_bf16.h>

typedef __attribute__((ext_vector_type(8))) __bf16 bf16x8;
typedef __attribute__((ext_vector_type(4))) float f32x4;
typedef unsigned short u16;
typedef unsigned long long u64;

#define SCALE2   (0.17677669529663687f * 1.44269504088896f)  // qk-scale * log2(e)
#define LOG2E    1.44269504088896f

static __device__ __forceinline__ u16 f2b(float f) {
    union { __bf16 h; u16 u; } z; z.h = (__bf16)f; return z.u;
}
static __device__ __forceinline__ float bu2f(u16 s) {
    union { unsigned u; float f; } z; z.u = ((unsigned)s) << 16; return z.f;
}
static __device__ __forceinline__ f32x4 mfma16(bf16x8 a, bf16x8 b, f32x4 c) {
    return __builtin_amdgcn_mfma_f32_16x16x32_bf16(a, b, c, 0, 0, 0);
}
static __device__ __forceinline__ bf16x8 ldfrag(const u16* p) {
    return *(const bf16x8*)p;
}
static __device__ __forceinline__ u64 pack4(float a, float b, float c, float d) {
    union { __bf16 h[4]; u64 q; } z;
    z.h[0] = (__bf16)a; z.h[1] = (__bf16)b; z.h[2] = (__bf16)c; z.h[3] = (__bf16)d;
    return z.q;
}
static __device__ __forceinline__ bf16x8 pack8(float4 a, float4 b) {
    union { __bf16 h[8]; bf16x8 v; } z;
    z.h[0] = (__bf16)a.x; z.h[1] = (__bf16)a.y; z.h[2] = (__bf16)a.z; z.h[3] = (__bf16)a.w;
    z.h[4] = (__bf16)b.x; z.h[5] = (__bf16)b.y; z.h[6] = (__bf16)b.z; z.h[7] = (__bf16)b.w;
    return z.v;
}
// ---- cross-lane reduces: R11-proven shfl_xor form (permlane asm was the
//      R12/R13 failure suspect; reverted pending a verified builtin path) ----
static __device__ __forceinline__ float red_sum_16_32(float v) {
    v += __shfl_xor(v, 16);
    v += __shfl_xor(v, 32);
    return v;
}
static __device__ __forceinline__ float red_max_16_32(float v) {
    v = fmaxf(v, __shfl_xor(v, 16));
    v = fmaxf(v, __shfl_xor(v, 32));
    return v;
}
// ---- XOR-swizzled LDS accessors: 64-u16 (128 B) rows ----------------------
static __device__ __forceinline__ void st4(u16* base, int row, int col, u64 v) {
    *(u64*)&base[(row << 6) + (col ^ ((row & 7) << 3))] = v;
}
static __device__ __forceinline__ bf16x8 ld8(const u16* base, int row, int col) {
    return *(const bf16x8*)&base[(row << 6) + (col ^ ((row & 7) << 3))];
}

// ============================================================================
// Prep 1: swizzle w_qkv / w_out into MFMA fragment order (bf16) in workspace.
// ============================================================================
__global__ __launch_bounds__(256) void prep_weights(
    const float* __restrict__ w_qkv, const float* __restrict__ w_out,
    u16* __restrict__ wsq, u16* __restrict__ wso)
{
    int idx = blockIdx.x * 256 + threadIdx.x;
    if (idx < 27648) {
        int e = idx & 7, lA = (idx >> 3) & 63;
        int rest = idx >> 9;              // h*18 + sec*3 + ks
        int ks = rest % 3, sec = (rest / 3) % 6, h = rest / 18;
        int krow = ks * 32 + (lA >> 4) * 8 + e;
        int n = lA & 15;
        int gcol;
        if (sec < 2)      gcol = h * 32 + sec * 16 + n;              // Q
        else if (sec < 4) gcol = 96 + h * 32 + (sec - 2) * 16 + n;   // K
        else              gcol = 192 + h * 32 + (sec - 4) * 16 + n;  // V
        wsq[idx] = f2b(w_qkv[krow * 288 + gcol]);
    }
    if (idx < 9216) {
        int e = idx & 7, lA = (idx >> 3) & 63;
        int rest = idx >> 9;              // h*6 + nt
        int nt = rest % 6, h = rest / 6;
        int krow = h * 32 + (lA >> 4) * 8 + e;
        wso[idx] = f2b(w_out[krow * 96 + nt * 16 + (lA & 15)]);
    }
}

// ============================================================================
// Prep 2: bias+mask table, LANE-CONTIGUOUS layout:
// biasT[t][w][l][jt][reg] — each lane's 16 floats are one 64 B block.
// ============================================================================
__global__ __launch_bounds__(256) void prep_bias(
    const float* __restrict__ pos_emb, float* __restrict__ biasT)
{
    int idx = blockIdx.x * 256 + threadIdx.x;    // 0..16383
    if (idx >= 16384) return;
    int reg = idx & 3, jt = (idx >> 2) & 3, l = (idx >> 4) & 63;
    int w = (idx >> 10) & 3, t = idx >> 12;
    int i = 16 * w + (l & 15);                   // query token (S^T col)
    int j = jt * 16 + (l >> 4) * 4 + reg;        // key token (S^T row block)
    float v;
    if (j >= 49) v = -1e30f;             // exp2 -> 0 exactly
    else if (i >= 49) v = 0.f;           // row discarded later; keep finite
    else {
        int ir = i / 7, ic = i - ir * 7, jr = j / 7, jc = j - jr * 7;
        v = pos_emb[(jr - ir + 6) * 13 + (jc - ic + 6)] * LOG2E;
        if ((t & 1) && ((ir >= 4) != (jr >= 4))) v = -1e30f;
        if ((t & 2) && ((ic >= 4) != (jc >= 4))) v = -1e30f;
    }
    biasT[idx] = v;
}

// ============================================================================
// Fused MFMA swin block: swapped-operand, swizzled LDS, double-buffered K/V^T,
// intra-head reorder (GEMM1(h+1) under the P roundtrip), setprio front.
// LDS 32 KB. One block per (batch, window); 4 waves.
// ============================================================================
__global__ __launch_bounds__(256, 4) void swin_attn_mfma(
    const float* __restrict__ x,
    const float* __restrict__ biasT,
    const u16*  __restrict__ wsq,
    const u16*  __restrict__ wso,
    const float* __restrict__ b_out,
    float* __restrict__ outf,        // f32 fallback (may be null)
    u16*  __restrict__ outw,         // bf16 intermediate (may be null)
    float* __restrict__ psum_win,    // [8*1024][96]
    float* __restrict__ pmax_win,    // [8*1024][96]
    int write_bf16)
{
    // row=token: cols 0-31 Q (own-row reads; O overwrites), cols 32-63 K.
    __shared__ __attribute__((aligned(16))) u16 qk0_s[64 * 64];  // 8192 B
    __shared__ __attribute__((aligned(16))) u16 qk1_s[64 * 64];  // 8192 B
    __shared__ __attribute__((aligned(16))) u16 vT0_s[32 * 64];  // 4096 B
    __shared__ __attribute__((aligned(16))) u16 vT1_s[32 * 64];  // 4096 B
    __shared__ __attribute__((aligned(16))) u16 p_s[64 * 64];    // 8192 B

    const int blk = blockIdx.x;
    const int b = blk >> 10, win = blk & 1023;
    const int wh = win >> 5, ww = win & 31;
    const int tid = threadIdx.x;
    const int w = tid >> 6, l = tid & 63, lr = l & 15, lg = l >> 4;
    const int myrow = 16 * w + lr;        // this lane's token

    // ---- bias: 64 B contiguous per lane, issued first (L2-resident table) ----
    const int wtype = ((wh == 31) ? 1 : 0) + ((ww == 31) ? 2 : 0);
    const float4* btp = (const float4*)(biasT + (((size_t)wtype * 4 + w) * 64 + l) * 16);
    const float4 bias0 = btp[0];
    const float4 bias1 = btp[1];
    const float4 bias2 = btp[2];
    const float4 bias3 = btp[3];

    // ---- X fragments direct from global ----
    bf16x8 ax0, ax1, ax2;
    {
        int sr = wh * 7 + myrow / 7 + 3;  if (sr >= 224) sr -= 224;
        int sc = ww * 7 + myrow % 7 + 3;  if (sc >= 224) sc -= 224;
        const float* xr = x + (((size_t)b * 224 + sr) * 224 + sc) * 96 + lg * 8;
        ax0 = pack8(*(const float4*)(xr +  0), *(const float4*)(xr +  4));
        ax1 = pack8(*(const float4*)(xr + 32), *(const float4*)(xr + 36));
        ax2 = pack8(*(const float4*)(xr + 64), *(const float4*)(xr + 68));
    }

    const u16* wsq_l = wsq + l * 8;
    const u16* wso_l = wso + l * 8;

    f32x4 proj[6];
    #pragma unroll
    for (int nt = 0; nt < 6; ++nt) proj[nt] = (f32x4){0.f, 0.f, 0.f, 0.f};

    // ---- GEMM1 for head h into (qkb, vtb) ----
    auto GEMM1 = [&](int h, u16* qkb, u16* vtb) {
        #pragma unroll
        for (int sec = 0; sec < 6; ++sec) {
            const u16* wb = wsq_l + (size_t)(h * 18 + sec * 3) * 512;
            f32x4 c = {0.f, 0.f, 0.f, 0.f};
            if (sec < 4) {        // Q/K swapped: C col = token(lr), rows = d
                c = mfma16(ldfrag(wb), ax0, c);
                c = mfma16(ldfrag(wb + 512), ax1, c);
                c = mfma16(ldfrag(wb + 1024), ax2, c);
                st4(qkb, myrow, (sec < 2 ? 0 : 32) + (sec & 1) * 16 + lg * 4,
                    pack4(c[0], c[1], c[2], c[3]));
            } else {              // V unswapped: C col = d(lr), rows = token
                c = mfma16(ax0, ldfrag(wb), c);
                c = mfma16(ax1, ldfrag(wb + 512), c);
                c = mfma16(ax2, ldfrag(wb + 1024), c);
                st4(vtb, (sec - 4) * 16 + lr, 16 * w + lg * 4,
                    pack4(c[0], c[1], c[2], c[3]));
            }
        }
    };

    GEMM1(0, qk0_s, vT0_s);
    __syncthreads();              // K/V^T of head 0 visible

    #pragma unroll
    for (int h = 0; h < 3; ++h) {
        u16* qkb = (h & 1) ? qk1_s : qk0_s;
        u16* vtb = (h & 1) ? vT1_s : vT0_s;

        // ---- latency-critical front: GEMM2 + softmax (elevated priority) ----
        __builtin_amdgcn_s_setprio(1);
        bf16x8 bq = ld8(qkb, myrow, lg * 8);
        f32x4 S[4];
        #pragma unroll
        for (int jt = 0; jt < 4; ++jt) {
            f32x4 z = {0.f, 0.f, 0.f, 0.f};
            S[jt] = mfma16(ld8(qkb, jt * 16 + lr, 32 + lg * 8), bq, z);
        }

        float ssum;
        {
            float e0[4], e1[4], e2[4], e3[4];
            float s = 0.f;
            #pragma unroll
            for (int reg = 0; reg < 4; ++reg) {
                e0[reg] = exp2f(fmaf(S[0][reg], SCALE2, bias0[reg])); s += e0[reg];
                e1[reg] = exp2f(fmaf(S[1][reg], SCALE2, bias1[reg])); s += e1[reg];
                e2[reg] = exp2f(fmaf(S[2][reg], SCALE2, bias2[reg])); s += e2[reg];
                e3[reg] = exp2f(fmaf(S[3][reg], SCALE2, bias3[reg])); s += e3[reg];
            }
            ssum = red_sum_16_32(s);
            st4(p_s, myrow,      lg * 4, pack4(e0[0], e0[1], e0[2], e0[3]));
            st4(p_s, myrow, 16 + lg * 4, pack4(e1[0], e1[1], e1[2], e1[3]));
            st4(p_s, myrow, 32 + lg * 4, pack4(e2[0], e2[1], e2[2], e2[3]));
            st4(p_s, myrow, 48 + lg * 4, pack4(e3[0], e3[1], e3[2], e3[3]));
        }
        float inv = 1.f / ssum;
        // issue P read-back now; completes while GEMM1(h+1) runs
        bf16x8 bp0 = ld8(p_s, myrow, lg * 8);
        bf16x8 bp1 = ld8(p_s, myrow, 32 + lg * 8);
        __builtin_amdgcn_s_setprio(0);

        // ---- produce next head's K/V^T (its VMEM stall hides P roundtrip) ----
        if (h < 2) GEMM1(h + 1, (h & 1) ? qk0_s : qk1_s, (h & 1) ? vT0_s : vT1_s);

        // ---- GEMM3: O^T = V^T @ P^T (deferred normalization by inv) ----
        #pragma unroll
        for (int mt = 0; mt < 2; ++mt) {
            f32x4 c = {0.f, 0.f, 0.f, 0.f};
            c = mfma16(ld8(vtb, mt * 16 + lr,  0 + lg * 8), bp0, c);
            c = mfma16(ld8(vtb, mt * 16 + lr, 32 + lg * 8), bp1, c);
            // O -> own-row Q cols of qkb (Q only ever read own-row; done above)
            st4(qkb, myrow, mt * 16 + lg * 4,
                pack4(c[0] * inv, c[1] * inv, c[2] * inv, c[3] * inv));
        }

        // ---- GEMM4: proj += O @ Wout_h ----
        bf16x8 ao = ld8(qkb, myrow, lg * 8);
        #pragma unroll
        for (int nt = 0; nt < 6; ++nt)
            proj[nt] = mfma16(ao, ldfrag(wso_l + (size_t)(h * 6 + nt) * 512),
                              proj[nt]);

        if (h < 2) __syncthreads();   // next head's K/V^T ready; bufs swap safe
    }

    // ---- epilogue: +b_out, write out (rolled back), fused col sum/max ----
    float bo[6];
    #pragma unroll
    for (int nt = 0; nt < 6; ++nt) bo[nt] = b_out[nt * 16 + lr];
    float csum[6], cmax[6];
    #pragma unroll
    for (int nt = 0; nt < 6; ++nt) { csum[nt] = 0.f; cmax[nt] = -1e30f; }
    const int tok0 = 16 * w + lg * 4;
    const int r0t = tok0 / 7, c0t = tok0 - r0t * 7;
    #pragma unroll
    for (int reg = 0; reg < 4; ++reg) {
        if (tok0 + reg < 49) {
            int rr = r0t, cc = c0t + reg;
            if (cc >= 7) { cc -= 7; rr += 1; }
            int sr = wh * 7 + rr + 3;  if (sr >= 224) sr -= 224;
            int sc = ww * 7 + cc + 3;  if (sc >= 224) sc -= 224;
            size_t o0 = (((size_t)b * 224 + sr) * 224 + sc) * 96 + lr;
            #pragma unroll
            for (int nt = 0; nt < 6; ++nt) {
                float v = proj[nt][reg] + bo[nt];
                if (write_bf16) outw[o0 + nt * 16] = f2b(v);
                else            outf[o0 + nt * 16] = v;
                csum[nt] += v;
                cmax[nt] = fmaxf(cmax[nt], v);
            }
        }
    }
    #pragma unroll
    for (int nt = 0; nt < 6; ++nt) {
        csum[nt] = red_sum_16_32(csum[nt]);
        cmax[nt] = red_max_16_32(cmax[nt]);
    }
    // rsum/rmax reuse p_s; wait until all waves done with P/O reads.
    float* rsum = (float*)p_s;          // 384 floats
    float* rmax = rsum + 384;           // 384 floats
    __syncthreads();
    if (lg == 0) {
        #pragma unroll
        for (int nt = 0; nt < 6; ++nt) {
            rsum[w * 96 + nt * 16 + lr] = csum[nt];
            rmax[w * 96 + nt * 16 + lr] = cmax[nt];
        }
    }
    __syncthreads();
    if (tid < 96) {
        size_t o = ((size_t)b * 1024 + win) * 96 + tid;
        psum_win[o] = rsum[tid] + rsum[96 + tid] + rsum[192 + tid] + rsum[288 + tid];
        pmax_win[o] = fmaxf(fmaxf(rmax[tid], rmax[96 + tid]),
                            fmaxf(rmax[192 + tid], rmax[288 + tid]));
    }
}

// ============================================================================
// Gate: reduce 1024 per-window partials -> avg/max -> two MLPs -> sigmoid.
// ============================================================================
__global__ __launch_bounds__(384) void gate_kernel(
    const float* __restrict__ psum, const float* __restrict__ pmax,
    const float* __restrict__ w11, const float* __restrict__ b11,
    const float* __restrict__ w12, const float* __restrict__ b12,
    const float* __restrict__ w21, const float* __restrict__ b21,
    const float* __restrict__ w22, const float* __restrict__ b22,
    float* __restrict__ gate)
{
    const int b = blockIdx.x;
    const int tid = threadIdx.x;
    const int c = tid % 96, sub = tid / 96;
    __shared__ float ls[384], lm[384];
    __shared__ float avg[96], mx[96], h1[96], h2[96];

    float s = 0.f, m = -1e30f;
    for (int k = sub * 256; k < sub * 256 + 256; ++k) {
        size_t o = ((size_t)b * 1024 + k) * 96 + c;
        s += psum[o];
        m = fmaxf(m, pmax[o]);
    }
    ls[tid] = s; lm[tid] = m;
    __syncthreads();
    if (tid < 96) {
        s = ls[c] + ls[96 + c] + ls[192 + c] + ls[288 + c];
        m = fmaxf(fmaxf(lm[c], lm[96 + c]), fmaxf(lm[192 + c], lm[288 + c]));
        avg[c] = s * (1.0f / 50176.0f);
        mx[c]  = m;
    }
    __syncthreads();
    if (tid < 96) {
        float sa = b11[c], sm = b21[c];
        for (int ic = 0; ic < 96; ++ic) {
            sa = fmaf(avg[ic], w11[ic * 96 + c], sa);
            sm = fmaf(mx[ic],  w21[ic * 96 + c], sm);
        }
        h1[c] = fmaxf(sa, 0.f);
        h2[c] = fmaxf(sm, 0.f);
    }
    __syncthreads();
    if (tid < 96) {
        float a = b12[c], m2 = b22[c];
        for (int hh = 0; hh < 96; ++hh) {
            a  = fmaf(h1[hh], w12[hh * 96 + c], a);
            m2 = fmaf(h2[hh], w22[hh * 96 + c], m2);
        }
        float g = a + m2;
        gate[b * 96 + c] = 1.0f / (1.0f + __expf(-g));
    }
}

// ============================================================================
// Final scale: out_f32 = bf16_ws * gate
// ============================================================================
__global__ __launch_bounds__(256) void scale_bf16_kernel(
    const u16* __restrict__ outw, float* __restrict__ out,
    const float* __restrict__ gate)
{
    const size_t total8 = 38535168u / 8;
    for (size_t i8 = (size_t)blockIdx.x * blockDim.x + threadIdx.x; i8 < total8;
         i8 += (size_t)gridDim.x * blockDim.x) {
        size_t base = i8 * 8;
        int c = (int)(base % 96);
        int b = (int)(base / ((size_t)50176 * 96));
        u64 pk0 = *(const u64*)(outw + base);
        u64 pk1 = *(const u64*)(outw + base + 4);
        float4 g0 = *(const float4*)(gate + b * 96 + c);
        float4 g1 = *(const float4*)(gate + b * 96 + c + 4);
        float4 o0, o1;
        o0.x = bu2f((u16)(pk0      )) * g0.x;
        o0.y = bu2f((u16)(pk0 >> 16)) * g0.y;
        o0.z = bu2f((u16)(pk0 >> 32)) * g0.z;
        o0.w = bu2f((u16)(pk0 >> 48)) * g0.w;
        o1.x = bu2f((u16)(pk1      )) * g1.x;
        o1.y = bu2f((u16)(pk1 >> 16)) * g1.y;
        o1.z = bu2f((u16)(pk1 >> 32)) * g1.z;
        o1.w = bu2f((u16)(pk1 >> 48)) * g1.w;
        *(float4*)(out + base)     = o0;
        *(float4*)(out + base + 4) = o1;
    }
}

// f32 in-place fallback
__global__ __launch_bounds__(256) void scale_f32_kernel(
    float* __restrict__ out, const float* __restrict__ gate)
{
    const size_t total4 = 38535168u / 4;
    for (size_t i4 = (size_t)blockIdx.x * blockDim.x + threadIdx.x; i4 < total4;
         i4 += (size_t)gridDim.x * blockDim.x) {
        size_t base = i4 * 4;
        int c = (int)(base % 96);
        int b = (int)(base / ((size_t)50176 * 96));
        float4 u = ((const float4*)out)[i4];
        float4 g = *(const float4*)(gate + b * 96 + c);
        float4 o;
        o.x = u.x * g.x; o.y = u.y * g.y; o.z = u.z * g.z; o.w = u.w * g.w;
        ((float4*)out)[i4] = o;
    }
}

extern "C" void kernel_launch(void* const* d_in, const int* in_sizes, int n_in,
                              void* d_out, int out_size, void* d_ws, size_t ws_size,
                              hipStream_t stream) {
    const float* x     = (const float*)d_in[0];
    const float* wqkv  = (const float*)d_in[1];
    const float* pos   = (const float*)d_in[2];
    const float* wout  = (const float*)d_in[3];
    const float* bout  = (const float*)d_in[4];
    const float* m1w1  = (const float*)d_in[5];
    const float* m1b1  = (const float*)d_in[6];
    const float* m1w2  = (const float*)d_in[7];
    const float* m1b2  = (const float*)d_in[8];
    const float* m2w1  = (const float*)d_in[9];
    const float* m2b1  = (const float*)d_in[10];
    const float* m2w2  = (const float*)d_in[11];
    const float* m2b2  = (const float*)d_in[12];
    float* out = (float*)d_out;

    float* psum_win = (float*)d_ws;             // 3.15 MB
    float* pmax_win = psum_win + 8 * 1024 * 96; // 3.15 MB
    float* gatep    = pmax_win + 8 * 1024 * 96; // 3 KB
    u16*   wsq      = (u16*)(gatep + 8 * 96);   // 55 KB
    u16*   wso      = wsq + 27648;              // 18 KB
    float* biasT    = (float*)(wso + 9216);     // 64 KB (lane-contiguous layout)
    u16*   outw     = (u16*)(biasT + 16384);    // 77.1 MB (bf16 intermediate)

    const size_t base_bytes = (size_t)((char*)outw - (char*)d_ws);
    const size_t outw_bytes = (size_t)8 * 50176 * 96 * sizeof(u16);
    const int use_bf16 = (ws_size >= base_bytes + outw_bytes) ? 1 : 0;

    hipLaunchKernelGGL(prep_weights, dim3(108), dim3(256), 0, stream,
                       wqkv, wout, wsq, wso);
    hipLaunchKernelGGL(prep_bias, dim3(64), dim3(256), 0, stream,
                       pos, biasT);
    hipLaunchKernelGGL(swin_attn_mfma, dim3(8192), dim3(256), 0, stream,
                       x, biasT, wsq, wso, bout,
                       use_bf16 ? nullptr : out, use_bf16 ? outw : nullptr,
                       psum_win, pmax_win, use_bf16);
    hipLaunchKernelGGL(gate_kernel, dim3(8), dim3(384), 0, stream,
                       psum_win, pmax_win, m1w1, m1b1, m1w2, m1b2,
                       m2w1, m2b1, m2w2, m2b2, gatep);
    if (use_bf16) {
        hipLaunchKernelGGL(scale_bf16_kernel, dim3(2048), dim3(256), 0, stream,
                           outw, out, gatep);
    } else {
        hipLaunchKernelGGL(scale_f32_kernel, dim3(2048), dim3(256), 0, stream,
                           out, gatep);
    }
}

// Round 15
// 240.077 us; speedup vs baseline: 1.0237x; 1.0237x over previous
//
#include <hip/hip_runtime.h>
#include <hip/hip_bf16.h>

typedef __attribute__((ext_vector_type(8))) __bf16 bf16x8;
typedef __attribute__((ext_vector_type(4))) float f32x4;
typedef unsigned short u16;
typedef unsigned long long u64;

#define SCALE2   (0.17677669529663687f * 1.44269504088896f)  // qk-scale * log2(e)
#define LOG2E    1.44269504088896f

static __device__ __forceinline__ u16 f2b(float f) {
    union { __bf16 h; u16 u; } z; z.h = (__bf16)f; return z.u;
}
static __device__ __forceinline__ float bu2f(u16 s) {
    union { unsigned u; float f; } z; z.u = ((unsigned)s) << 16; return z.f;
}
static __device__ __forceinline__ f32x4 mfma16(bf16x8 a, bf16x8 b, f32x4 c) {
    return __builtin_amdgcn_mfma_f32_16x16x32_bf16(a, b, c, 0, 0, 0);
}
static __device__ __forceinline__ bf16x8 ldfrag(const u16* p) {
    return *(const bf16x8*)p;
}
static __device__ __forceinline__ u64 pack4(float a, float b, float c, float d) {
    union { __bf16 h[4]; u64 q; } z;
    z.h[0] = (__bf16)a; z.h[1] = (__bf16)b; z.h[2] = (__bf16)c; z.h[3] = (__bf16)d;
    return z.q;
}
static __device__ __forceinline__ bf16x8 pack8(float4 a, float4 b) {
    union { __bf16 h[8]; bf16x8 v; } z;
    z.h[0] = (__bf16)a.x; z.h[1] = (__bf16)a.y; z.h[2] = (__bf16)a.z; z.h[3] = (__bf16)a.w;
    z.h[4] = (__bf16)b.x; z.h[5] = (__bf16)b.y; z.h[6] = (__bf16)b.z; z.h[7] = (__bf16)b.w;
    return z.v;
}
// ---- cross-lane reduces: shfl_xor (R11-proven) ----------------------------
static __device__ __forceinline__ float red_sum_16_32(float v) {
    v += __shfl_xor(v, 16);
    v += __shfl_xor(v, 32);
    return v;
}
static __device__ __forceinline__ float red_max_16_32(float v) {
    v = fmaxf(v, __shfl_xor(v, 16));
    v = fmaxf(v, __shfl_xor(v, 32));
    return v;
}
// ---- XOR-swizzled LDS accessors: 64-u16 (128 B) rows ----------------------
static __device__ __forceinline__ void st4(u16* base, int row, int col, u64 v) {
    *(u64*)&base[(row << 6) + (col ^ ((row & 7) << 3))] = v;
}
static __device__ __forceinline__ bf16x8 ld8(const u16* base, int row, int col) {
    return *(const bf16x8*)&base[(row << 6) + (col ^ ((row & 7) << 3))];
}

// ============================================================================
// Prep 1: swizzle w_qkv / w_out into MFMA fragment order (bf16) in workspace.
// ============================================================================
__global__ __launch_bounds__(256) void prep_weights(
    const float* __restrict__ w_qkv, const float* __restrict__ w_out,
    u16* __restrict__ wsq, u16* __restrict__ wso)
{
    int idx = blockIdx.x * 256 + threadIdx.x;
    if (idx < 27648) {
        int e = idx & 7, lA = (idx >> 3) & 63;
        int rest = idx >> 9;              // h*18 + sec*3 + ks
        int ks = rest % 3, sec = (rest / 3) % 6, h = rest / 18;
        int krow = ks * 32 + (lA >> 4) * 8 + e;
        int n = lA & 15;
        int gcol;
        if (sec < 2)      gcol = h * 32 + sec * 16 + n;              // Q
        else if (sec < 4) gcol = 96 + h * 32 + (sec - 2) * 16 + n;   // K
        else              gcol = 192 + h * 32 + (sec - 4) * 16 + n;  // V
        wsq[idx] = f2b(w_qkv[krow * 288 + gcol]);
    }
    if (idx < 9216) {
        int e = idx & 7, lA = (idx >> 3) & 63;
        int rest = idx >> 9;              // h*6 + nt
        int nt = rest % 6, h = rest / 6;
        int krow = h * 32 + (lA >> 4) * 8 + e;
        wso[idx] = f2b(w_out[krow * 96 + nt * 16 + (lA & 15)]);
    }
}

// ============================================================================
// Prep 2: bias+mask table, LANE-CONTIGUOUS layout:
// biasT[t][w][l][jt][reg] — each lane's 16 floats are one 64 B block.
// ============================================================================
__global__ __launch_bounds__(256) void prep_bias(
    const float* __restrict__ pos_emb, float* __restrict__ biasT)
{
    int idx = blockIdx.x * 256 + threadIdx.x;    // 0..16383
    if (idx >= 16384) return;
    int reg = idx & 3, jt = (idx >> 2) & 3, l = (idx >> 4) & 63;
    int w = (idx >> 10) & 3, t = idx >> 12;
    int i = 16 * w + (l & 15);                   // query token (S^T col)
    int j = jt * 16 + (l >> 4) * 4 + reg;        // key token (S^T row block)
    float v;
    if (j >= 49) v = -1e30f;             // exp2 -> 0 exactly
    else if (i >= 49) v = 0.f;           // row discarded later; keep finite
    else {
        int ir = i / 7, ic = i - ir * 7, jr = j / 7, jc = j - jr * 7;
        v = pos_emb[(jr - ir + 6) * 13 + (jc - ic + 6)] * LOG2E;
        if ((t & 1) && ((ir >= 4) != (jr >= 4))) v = -1e30f;
        if ((t & 2) && ((ic >= 4) != (jc >= 4))) v = -1e30f;
    }
    biasT[idx] = v;
}

// ============================================================================
// Fused MFMA swin block: R11 structure exactly (GEMM1(h+1) issued FIRST so its
// VMEM/MFMA latency overlaps the consumer chain), plus setprio(1) around the
// latency-critical consumer chain (GEMM2 -> softmax -> P roundtrip -> GEMM3/4).
// LDS 32 KB. One block per (batch, window); 4 waves.
// ============================================================================
__global__ __launch_bounds__(256, 4) void swin_attn_mfma(
    const float* __restrict__ x,
    const float* __restrict__ biasT,
    const u16*  __restrict__ wsq,
    const u16*  __restrict__ wso,
    const float* __restrict__ b_out,
    float* __restrict__ outf,        // f32 fallback (may be null)
    u16*  __restrict__ outw,         // bf16 intermediate (may be null)
    float* __restrict__ psum_win,    // [8*1024][96]
    float* __restrict__ pmax_win,    // [8*1024][96]
    int write_bf16)
{
    // row=token: cols 0-31 Q (own-row reads; O overwrites), cols 32-63 K.
    __shared__ __attribute__((aligned(16))) u16 qk0_s[64 * 64];  // 8192 B
    __shared__ __attribute__((aligned(16))) u16 qk1_s[64 * 64];  // 8192 B
    __shared__ __attribute__((aligned(16))) u16 vT0_s[32 * 64];  // 4096 B
    __shared__ __attribute__((aligned(16))) u16 vT1_s[32 * 64];  // 4096 B
    __shared__ __attribute__((aligned(16))) u16 p_s[64 * 64];    // 8192 B

    const int blk = blockIdx.x;
    const int b = blk >> 10, win = blk & 1023;
    const int wh = win >> 5, ww = win & 31;
    const int tid = threadIdx.x;
    const int w = tid >> 6, l = tid & 63, lr = l & 15, lg = l >> 4;
    const int myrow = 16 * w + lr;        // this lane's token

    // ---- bias: 64 B contiguous per lane, issued first (L2-resident table) ----
    const int wtype = ((wh == 31) ? 1 : 0) + ((ww == 31) ? 2 : 0);
    const float4* btp = (const float4*)(biasT + (((size_t)wtype * 4 + w) * 64 + l) * 16);
    const float4 bias0 = btp[0];
    const float4 bias1 = btp[1];
    const float4 bias2 = btp[2];
    const float4 bias3 = btp[3];

    // ---- X fragments direct from global ----
    bf16x8 ax0, ax1, ax2;
    {
        int sr = wh * 7 + myrow / 7 + 3;  if (sr >= 224) sr -= 224;
        int sc = ww * 7 + myrow % 7 + 3;  if (sc >= 224) sc -= 224;
        const float* xr = x + (((size_t)b * 224 + sr) * 224 + sc) * 96 + lg * 8;
        ax0 = pack8(*(const float4*)(xr +  0), *(const float4*)(xr +  4));
        ax1 = pack8(*(const float4*)(xr + 32), *(const float4*)(xr + 36));
        ax2 = pack8(*(const float4*)(xr + 64), *(const float4*)(xr + 68));
    }

    const u16* wsq_l = wsq + l * 8;
    const u16* wso_l = wso + l * 8;

    f32x4 proj[6];
    #pragma unroll
    for (int nt = 0; nt < 6; ++nt) proj[nt] = (f32x4){0.f, 0.f, 0.f, 0.f};

    // ---- GEMM1 for head h into (qkb, vtb) ----
    auto GEMM1 = [&](int h, u16* qkb, u16* vtb) {
        #pragma unroll
        for (int sec = 0; sec < 6; ++sec) {
            const u16* wb = wsq_l + (size_t)(h * 18 + sec * 3) * 512;
            f32x4 c = {0.f, 0.f, 0.f, 0.f};
            if (sec < 4) {        // Q/K swapped: C col = token(lr), rows = d
                c = mfma16(ldfrag(wb), ax0, c);
                c = mfma16(ldfrag(wb + 512), ax1, c);
                c = mfma16(ldfrag(wb + 1024), ax2, c);
                st4(qkb, myrow, (sec < 2 ? 0 : 32) + (sec & 1) * 16 + lg * 4,
                    pack4(c[0], c[1], c[2], c[3]));
            } else {              // V unswapped: C col = d(lr), rows = token
                c = mfma16(ax0, ldfrag(wb), c);
                c = mfma16(ax1, ldfrag(wb + 512), c);
                c = mfma16(ax2, ldfrag(wb + 1024), c);
                st4(vtb, (sec - 4) * 16 + lr, 16 * w + lg * 4,
                    pack4(c[0], c[1], c[2], c[3]));
            }
        }
    };

    GEMM1(0, qk0_s, vT0_s);
    __syncthreads();              // K/V^T of head 0 visible

    #pragma unroll
    for (int h = 0; h < 3; ++h) {
        u16* qkb = (h & 1) ? qk1_s : qk0_s;
        u16* vtb = (h & 1) ? vT1_s : vT0_s;

        // pipeline: produce next head's K/V^T FIRST (R11 order) — its
        // VMEM/MFMA latency overlaps the consumer chain below.
        if (h < 2) GEMM1(h + 1, (h & 1) ? qk0_s : qk1_s, (h & 1) ? vT0_s : vT1_s);

        // ---- consumer chain at elevated priority (T5) ----
        __builtin_amdgcn_s_setprio(1);

        // ---- GEMM2: S^T = K @ Q^T ----
        bf16x8 bq = ld8(qkb, myrow, lg * 8);
        f32x4 S[4];
        #pragma unroll
        for (int jt = 0; jt < 4; ++jt) {
            f32x4 z = {0.f, 0.f, 0.f, 0.f};
            S[jt] = mfma16(ld8(qkb, jt * 16 + lr, 32 + lg * 8), bq, z);
        }

        // ---- softmax via exp2 (scale/bias pre-folded into table) ----
        float ssum;
        {
            float e0[4], e1[4], e2[4], e3[4];
            float s = 0.f;
            #pragma unroll
            for (int reg = 0; reg < 4; ++reg) {
                e0[reg] = exp2f(fmaf(S[0][reg], SCALE2, bias0[reg])); s += e0[reg];
                e1[reg] = exp2f(fmaf(S[1][reg], SCALE2, bias1[reg])); s += e1[reg];
                e2[reg] = exp2f(fmaf(S[2][reg], SCALE2, bias2[reg])); s += e2[reg];
                e3[reg] = exp2f(fmaf(S[3][reg], SCALE2, bias3[reg])); s += e3[reg];
            }
            ssum = red_sum_16_32(s);
            st4(p_s, myrow,      lg * 4, pack4(e0[0], e0[1], e0[2], e0[3]));
            st4(p_s, myrow, 16 + lg * 4, pack4(e1[0], e1[1], e1[2], e1[3]));
            st4(p_s, myrow, 32 + lg * 4, pack4(e2[0], e2[1], e2[2], e2[3]));
            st4(p_s, myrow, 48 + lg * 4, pack4(e3[0], e3[1], e3[2], e3[3]));
        }
        float inv = 1.f / ssum;

        // ---- GEMM3: O^T = V^T @ P^T (deferred normalization by inv) ----
        bf16x8 bp0 = ld8(p_s, myrow, lg * 8);
        bf16x8 bp1 = ld8(p_s, myrow, 32 + lg * 8);
        #pragma unroll
        for (int mt = 0; mt < 2; ++mt) {
            f32x4 c = {0.f, 0.f, 0.f, 0.f};
            c = mfma16(ld8(vtb, mt * 16 + lr,  0 + lg * 8), bp0, c);
            c = mfma16(ld8(vtb, mt * 16 + lr, 32 + lg * 8), bp1, c);
            // O -> own-row Q cols of qkb (Q only ever read own-row; done above)
            st4(qkb, myrow, mt * 16 + lg * 4,
                pack4(c[0] * inv, c[1] * inv, c[2] * inv, c[3] * inv));
        }

        // ---- GEMM4: proj += O @ Wout_h ----
        bf16x8 ao = ld8(qkb, myrow, lg * 8);
        #pragma unroll
        for (int nt = 0; nt < 6; ++nt)
            proj[nt] = mfma16(ao, ldfrag(wso_l + (size_t)(h * 6 + nt) * 512),
                              proj[nt]);

        __builtin_amdgcn_s_setprio(0);

        if (h < 2) __syncthreads();   // next head's K/V^T ready; bufs swap safe
    }

    // ---- epilogue: +b_out, write out (rolled back), fused col sum/max ----
    float bo[6];
    #pragma unroll
    for (int nt = 0; nt < 6; ++nt) bo[nt] = b_out[nt * 16 + lr];
    float csum[6], cmax[6];
    #pragma unroll
    for (int nt = 0; nt < 6; ++nt) { csum[nt] = 0.f; cmax[nt] = -1e30f; }
    const int tok0 = 16 * w + lg * 4;
    const int r0t = tok0 / 7, c0t = tok0 - r0t * 7;
    #pragma unroll
    for (int reg = 0; reg < 4; ++reg) {
        if (tok0 + reg < 49) {
            int rr = r0t, cc = c0t + reg;
            if (cc >= 7) { cc -= 7; rr += 1; }
            int sr = wh * 7 + rr + 3;  if (sr >= 224) sr -= 224;
            int sc = ww * 7 + cc + 3;  if (sc >= 224) sc -= 224;
            size_t o0 = (((size_t)b * 224 + sr) * 224 + sc) * 96 + lr;
            #pragma unroll
            for (int nt = 0; nt < 6; ++nt) {
                float v = proj[nt][reg] + bo[nt];
                if (write_bf16) outw[o0 + nt * 16] = f2b(v);
                else            outf[o0 + nt * 16] = v;
                csum[nt] += v;
                cmax[nt] = fmaxf(cmax[nt], v);
            }
        }
    }
    #pragma unroll
    for (int nt = 0; nt < 6; ++nt) {
        csum[nt] = red_sum_16_32(csum[nt]);
        cmax[nt] = red_max_16_32(cmax[nt]);
    }
    // rsum/rmax reuse p_s; wait until all waves done with P/O reads.
    float* rsum = (float*)p_s;          // 384 floats
    float* rmax = rsum + 384;           // 384 floats
    __syncthreads();
    if (lg == 0) {
        #pragma unroll
        for (int nt = 0; nt < 6; ++nt) {
            rsum[w * 96 + nt * 16 + lr] = csum[nt];
            rmax[w * 96 + nt * 16 + lr] = cmax[nt];
        }
    }
    __syncthreads();
    if (tid < 96) {
        size_t o = ((size_t)b * 1024 + win) * 96 + tid;
        psum_win[o] = rsum[tid] + rsum[96 + tid] + rsum[192 + tid] + rsum[288 + tid];
        pmax_win[o] = fmaxf(fmaxf(rmax[tid], rmax[96 + tid]),
                            fmaxf(rmax[192 + tid], rmax[288 + tid]));
    }
}

// ============================================================================
// Gate: reduce 1024 per-window partials -> avg/max -> two MLPs -> sigmoid.
// ============================================================================
__global__ __launch_bounds__(384) void gate_kernel(
    const float* __restrict__ psum, const float* __restrict__ pmax,
    const float* __restrict__ w11, const float* __restrict__ b11,
    const float* __restrict__ w12, const float* __restrict__ b12,
    const float* __restrict__ w21, const float* __restrict__ b21,
    const float* __restrict__ w22, const float* __restrict__ b22,
    float* __restrict__ gate)
{
    const int b = blockIdx.x;
    const int tid = threadIdx.x;
    const int c = tid % 96, sub = tid / 96;
    __shared__ float ls[384], lm[384];
    __shared__ float avg[96], mx[96], h1[96], h2[96];

    float s = 0.f, m = -1e30f;
    for (int k = sub * 256; k < sub * 256 + 256; ++k) {
        size_t o = ((size_t)b * 1024 + k) * 96 + c;
        s += psum[o];
        m = fmaxf(m, pmax[o]);
    }
    ls[tid] = s; lm[tid] = m;
    __syncthreads();
    if (tid < 96) {
        s = ls[c] + ls[96 + c] + ls[192 + c] + ls[288 + c];
        m = fmaxf(fmaxf(lm[c], lm[96 + c]), fmaxf(lm[192 + c], lm[288 + c]));
        avg[c] = s * (1.0f / 50176.0f);
        mx[c]  = m;
    }
    __syncthreads();
    if (tid < 96) {
        float sa = b11[c], sm = b21[c];
        for (int ic = 0; ic < 96; ++ic) {
            sa = fmaf(avg[ic], w11[ic * 96 + c], sa);
            sm = fmaf(mx[ic],  w21[ic * 96 + c], sm);
        }
        h1[c] = fmaxf(sa, 0.f);
        h2[c] = fmaxf(sm, 0.f);
    }
    __syncthreads();
    if (tid < 96) {
        float a = b12[c], m2 = b22[c];
        for (int hh = 0; hh < 96; ++hh) {
            a  = fmaf(h1[hh], w12[hh * 96 + c], a);
            m2 = fmaf(h2[hh], w22[hh * 96 + c], m2);
        }
        float g = a + m2;
        gate[b * 96 + c] = 1.0f / (1.0f + __expf(-g));
    }
}

// ============================================================================
// Final scale: out_f32 = bf16_ws * gate
// ============================================================================
__global__ __launch_bounds__(256) void scale_bf16_kernel(
    const u16* __restrict__ outw, float* __restrict__ out,
    const float* __restrict__ gate)
{
    const size_t total8 = 38535168u / 8;
    for (size_t i8 = (size_t)blockIdx.x * blockDim.x + threadIdx.x; i8 < total8;
         i8 += (size_t)gridDim.x * blockDim.x) {
        size_t base = i8 * 8;
        int c = (int)(base % 96);
        int b = (int)(base / ((size_t)50176 * 96));
        u64 pk0 = *(const u64*)(outw + base);
        u64 pk1 = *(const u64*)(outw + base + 4);
        float4 g0 = *(const float4*)(gate + b * 96 + c);
        float4 g1 = *(const float4*)(gate + b * 96 + c + 4);
        float4 o0, o1;
        o0.x = bu2f((u16)(pk0      )) * g0.x;
        o0.y = bu2f((u16)(pk0 >> 16)) * g0.y;
        o0.z = bu2f((u16)(pk0 >> 32)) * g0.z;
        o0.w = bu2f((u16)(pk0 >> 48)) * g0.w;
        o1.x = bu2f((u16)(pk1      )) * g1.x;
        o1.y = bu2f((u16)(pk1 >> 16)) * g1.y;
        o1.z = bu2f((u16)(pk1 >> 32)) * g1.z;
        o1.w = bu2f((u16)(pk1 >> 48)) * g1.w;
        *(float4*)(out + base)     = o0;
        *(float4*)(out + base + 4) = o1;
    }
}

// f32 in-place fallback
__global__ __launch_bounds__(256) void scale_f32_kernel(
    float* __restrict__ out, const float* __restrict__ gate)
{
    const size_t total4 = 38535168u / 4;
    for (size_t i4 = (size_t)blockIdx.x * blockDim.x + threadIdx.x; i4 < total4;
         i4 += (size_t)gridDim.x * blockDim.x) {
        size_t base = i4 * 4;
        int c = (int)(base % 96);
        int b = (int)(base / ((size_t)50176 * 96));
        float4 u = ((const float4*)out)[i4];
        float4 g = *(const float4*)(gate + b * 96 + c);
        float4 o;
        o.x = u.x * g.x; o.y = u.y * g.y; o.z = u.z * g.z; o.w = u.w * g.w;
        ((float4*)out)[i4] = o;
    }
}

extern "C" void kernel_launch(void* const* d_in, const int* in_sizes, int n_in,
                              void* d_out, int out_size, void* d_ws, size_t ws_size,
                              hipStream_t stream) {
    const float* x     = (const float*)d_in[0];
    const float* wqkv  = (const float*)d_in[1];
    const float* pos   = (const float*)d_in[2];
    const float* wout  = (const float*)d_in[3];
    const float* bout  = (const float*)d_in[4];
    const float* m1w1  = (const float*)d_in[5];
    const float* m1b1  = (const float*)d_in[6];
    const float* m1w2  = (const float*)d_in[7];
    const float* m1b2  = (const float*)d_in[8];
    const float* m2w1  = (const float*)d_in[9];
    const float* m2b1  = (const float*)d_in[10];
    const float* m2w2  = (const float*)d_in[11];
    const float* m2b2  = (const float*)d_in[12];
    float* out = (float*)d_out;

    float* psum_win = (float*)d_ws;             // 3.15 MB
    float* pmax_win = psum_win + 8 * 1024 * 96; // 3.15 MB
    float* gatep    = pmax_win + 8 * 1024 * 96; // 3 KB
    u16*   wsq      = (u16*)(gatep + 8 * 96);   // 55 KB
    u16*   wso      = wsq + 27648;              // 18 KB
    float* biasT    = (float*)(wso + 9216);     // 64 KB (lane-contiguous layout)
    u16*   outw     = (u16*)(biasT + 16384);    // 77.1 MB (bf16 intermediate)

    const size_t base_bytes = (size_t)((char*)outw - (char*)d_ws);
    const size_t outw_bytes = (size_t)8 * 50176 * 96 * sizeof(u16);
    const int use_bf16 = (ws_size >= base_bytes + outw_bytes) ? 1 : 0;

    hipLaunchKernelGGL(prep_weights, dim3(108), dim3(256), 0, stream,
                       wqkv, wout, wsq, wso);
    hipLaunchKernelGGL(prep_bias, dim3(64), dim3(256), 0, stream,
                       pos, biasT);
    hipLaunchKernelGGL(swin_attn_mfma, dim3(8192), dim3(256), 0, stream,
                       x, biasT, wsq, wso, bout,
                       use_bf16 ? nullptr : out, use_bf16 ? outw : nullptr,
                       psum_win, pmax_win, use_bf16);
    hipLaunchKernelGGL(gate_kernel, dim3(8), dim3(384), 0, stream,
                       psum_win, pmax_win, m1w1, m1b1, m1w2, m1b2,
                       m2w1, m2b1, m2w2, m2b2, gatep);
    if (use_bf16) {
        hipLaunchKernelGGL(scale_bf16_kernel, dim3(2048), dim3(256), 0, stream,
                           outw, out, gatep);
    } else {
        hipLaunchKernelGGL(scale_f32_kernel, dim3(2048), dim3(256), 0, stream,
                           out, gatep);
    }
}

// Round 16
// 227.031 us; speedup vs baseline: 1.0825x; 1.0575x over previous
//
#include <hip/hip_runtime.h>
#include <hip/hip_bf16.h>

typedef __attribute__((ext_vector_type(8))) __bf16 bf16x8;
typedef __attribute__((ext_vector_type(4))) float f32x4;
typedef unsigned short u16;
typedef unsigned long long u64;

#define SCALE2   (0.17677669529663687f * 1.44269504088896f)  // qk-scale * log2(e)
#define LOG2E    1.44269504088896f

static __device__ __forceinline__ u16 f2b(float f) {
    union { __bf16 h; u16 u; } z; z.h = (__bf16)f; return z.u;
}
static __device__ __forceinline__ float bu2f(u16 s) {
    union { unsigned u; float f; } z; z.u = ((unsigned)s) << 16; return z.f;
}
static __device__ __forceinline__ f32x4 mfma16(bf16x8 a, bf16x8 b, f32x4 c) {
    return __builtin_amdgcn_mfma_f32_16x16x32_bf16(a, b, c, 0, 0, 0);
}
static __device__ __forceinline__ bf16x8 ldfrag(const u16* p) {
    return *(const bf16x8*)p;
}
static __device__ __forceinline__ u64 pack4(float a, float b, float c, float d) {
    union { __bf16 h[4]; u64 q; } z;
    z.h[0] = (__bf16)a; z.h[1] = (__bf16)b; z.h[2] = (__bf16)c; z.h[3] = (__bf16)d;
    return z.q;
}
static __device__ __forceinline__ bf16x8 pack8(float4 a, float4 b) {
    union { __bf16 h[8]; bf16x8 v; } z;
    z.h[0] = (__bf16)a.x; z.h[1] = (__bf16)a.y; z.h[2] = (__bf16)a.z; z.h[3] = (__bf16)a.w;
    z.h[4] = (__bf16)b.x; z.h[5] = (__bf16)b.y; z.h[6] = (__bf16)b.z; z.h[7] = (__bf16)b.w;
    return z.v;
}
// ---- cross-lane reduces: shfl_xor (R11-proven) ----------------------------
static __device__ __forceinline__ float red_sum_16_32(float v) {
    v += __shfl_xor(v, 16);
    v += __shfl_xor(v, 32);
    return v;
}
static __device__ __forceinline__ float red_max_16_32(float v) {
    v = fmaxf(v, __shfl_xor(v, 16));
    v = fmaxf(v, __shfl_xor(v, 32));
    return v;
}
// ---- XOR-swizzled LDS accessors: 64-u16 (128 B) rows ----------------------
static __device__ __forceinline__ void st4(u16* base, int row, int col, u64 v) {
    *(u64*)&base[(row << 6) + (col ^ ((row & 7) << 3))] = v;
}
static __device__ __forceinline__ bf16x8 ld8(const u16* base, int row, int col) {
    return *(const bf16x8*)&base[(row << 6) + (col ^ ((row & 7) << 3))];
}

// ============================================================================
// Prep 1: swizzle w_qkv / w_out into MFMA fragment order (bf16) in workspace.
// ============================================================================
__global__ __launch_bounds__(256) void prep_weights(
    const float* __restrict__ w_qkv, const float* __restrict__ w_out,
    u16* __restrict__ wsq, u16* __restrict__ wso)
{
    int idx = blockIdx.x * 256 + threadIdx.x;
    if (idx < 27648) {
        int e = idx & 7, lA = (idx >> 3) & 63;
        int rest = idx >> 9;              // h*18 + sec*3 + ks
        int ks = rest % 3, sec = (rest / 3) % 6, h = rest / 18;
        int krow = ks * 32 + (lA >> 4) * 8 + e;
        int n = lA & 15;
        int gcol;
        if (sec < 2)      gcol = h * 32 + sec * 16 + n;              // Q
        else if (sec < 4) gcol = 96 + h * 32 + (sec - 2) * 16 + n;   // K
        else              gcol = 192 + h * 32 + (sec - 4) * 16 + n;  // V
        wsq[idx] = f2b(w_qkv[krow * 288 + gcol]);
    }
    if (idx < 9216) {
        int e = idx & 7, lA = (idx >> 3) & 63;
        int rest = idx >> 9;              // h*6 + nt
        int nt = rest % 6, h = rest / 6;
        int krow = h * 32 + (lA >> 4) * 8 + e;
        wso[idx] = f2b(w_out[krow * 96 + nt * 16 + (lA & 15)]);
    }
}

// ============================================================================
// Prep 2: bias+mask table, LANE-CONTIGUOUS layout:
// biasT[t][w][l][jt][reg] — each lane's 16 floats are one 64 B block.
// ============================================================================
__global__ __launch_bounds__(256) void prep_bias(
    const float* __restrict__ pos_emb, float* __restrict__ biasT)
{
    int idx = blockIdx.x * 256 + threadIdx.x;    // 0..16383
    if (idx >= 16384) return;
    int reg = idx & 3, jt = (idx >> 2) & 3, l = (idx >> 4) & 63;
    int w = (idx >> 10) & 3, t = idx >> 12;
    int i = 16 * w + (l & 15);                   // query token (S^T col)
    int j = jt * 16 + (l >> 4) * 4 + reg;        // key token (S^T row block)
    float v;
    if (j >= 49) v = -1e30f;             // exp2 -> 0 exactly
    else if (i >= 49) v = 0.f;           // row discarded later; keep finite
    else {
        int ir = i / 7, ic = i - ir * 7, jr = j / 7, jc = j - jr * 7;
        v = pos_emb[(jr - ir + 6) * 13 + (jc - ic + 6)] * LOG2E;
        if ((t & 1) && ((ir >= 4) != (jr >= 4))) v = -1e30f;
        if ((t & 2) && ((ic >= 4) != (jc >= 4))) v = -1e30f;
    }
    biasT[idx] = v;
}

// ============================================================================
// Fused MFMA swin block — R11 configuration (measured best: 167 µs):
// swapped-operand MFMA, XOR-swizzled LDS, double-buffered K/V^T with
// GEMM1(h+1)-first pipeline, lane-contiguous bias table, shfl_xor reduces.
// No setprio (A/B: −8%), no intra-head reorder (A/B: −11%).
// LDS 32 KB. One block per (batch, window); 4 waves.
// ============================================================================
__global__ __launch_bounds__(256, 4) void swin_attn_mfma(
    const float* __restrict__ x,
    const float* __restrict__ biasT,
    const u16*  __restrict__ wsq,
    const u16*  __restrict__ wso,
    const float* __restrict__ b_out,
    float* __restrict__ outf,        // f32 fallback (may be null)
    u16*  __restrict__ outw,         // bf16 intermediate (may be null)
    float* __restrict__ psum_win,    // [8*1024][96]
    float* __restrict__ pmax_win,    // [8*1024][96]
    int write_bf16)
{
    // row=token: cols 0-31 Q (own-row reads; O overwrites), cols 32-63 K.
    __shared__ __attribute__((aligned(16))) u16 qk0_s[64 * 64];  // 8192 B
    __shared__ __attribute__((aligned(16))) u16 qk1_s[64 * 64];  // 8192 B
    __shared__ __attribute__((aligned(16))) u16 vT0_s[32 * 64];  // 4096 B
    __shared__ __attribute__((aligned(16))) u16 vT1_s[32 * 64];  // 4096 B
    __shared__ __attribute__((aligned(16))) u16 p_s[64 * 64];    // 8192 B

    const int blk = blockIdx.x;
    const int b = blk >> 10, win = blk & 1023;
    const int wh = win >> 5, ww = win & 31;
    const int tid = threadIdx.x;
    const int w = tid >> 6, l = tid & 63, lr = l & 15, lg = l >> 4;
    const int myrow = 16 * w + lr;        // this lane's token

    // ---- bias: 64 B contiguous per lane, issued first (L2-resident table) ----
    const int wtype = ((wh == 31) ? 1 : 0) + ((ww == 31) ? 2 : 0);
    const float4* btp = (const float4*)(biasT + (((size_t)wtype * 4 + w) * 64 + l) * 16);
    const float4 bias0 = btp[0];
    const float4 bias1 = btp[1];
    const float4 bias2 = btp[2];
    const float4 bias3 = btp[3];

    // ---- X fragments direct from global ----
    bf16x8 ax0, ax1, ax2;
    {
        int sr = wh * 7 + myrow / 7 + 3;  if (sr >= 224) sr -= 224;
        int sc = ww * 7 + myrow % 7 + 3;  if (sc >= 224) sc -= 224;
        const float* xr = x + (((size_t)b * 224 + sr) * 224 + sc) * 96 + lg * 8;
        ax0 = pack8(*(const float4*)(xr +  0), *(const float4*)(xr +  4));
        ax1 = pack8(*(const float4*)(xr + 32), *(const float4*)(xr + 36));
        ax2 = pack8(*(const float4*)(xr + 64), *(const float4*)(xr + 68));
    }

    const u16* wsq_l = wsq + l * 8;
    const u16* wso_l = wso + l * 8;

    f32x4 proj[6];
    #pragma unroll
    for (int nt = 0; nt < 6; ++nt) proj[nt] = (f32x4){0.f, 0.f, 0.f, 0.f};

    // ---- GEMM1 for head h into (qkb, vtb) ----
    auto GEMM1 = [&](int h, u16* qkb, u16* vtb) {
        #pragma unroll
        for (int sec = 0; sec < 6; ++sec) {
            const u16* wb = wsq_l + (size_t)(h * 18 + sec * 3) * 512;
            f32x4 c = {0.f, 0.f, 0.f, 0.f};
            if (sec < 4) {        // Q/K swapped: C col = token(lr), rows = d
                c = mfma16(ldfrag(wb), ax0, c);
                c = mfma16(ldfrag(wb + 512), ax1, c);
                c = mfma16(ldfrag(wb + 1024), ax2, c);
                st4(qkb, myrow, (sec < 2 ? 0 : 32) + (sec & 1) * 16 + lg * 4,
                    pack4(c[0], c[1], c[2], c[3]));
            } else {              // V unswapped: C col = d(lr), rows = token
                c = mfma16(ax0, ldfrag(wb), c);
                c = mfma16(ax1, ldfrag(wb + 512), c);
                c = mfma16(ax2, ldfrag(wb + 1024), c);
                st4(vtb, (sec - 4) * 16 + lr, 16 * w + lg * 4,
                    pack4(c[0], c[1], c[2], c[3]));
            }
        }
    };

    GEMM1(0, qk0_s, vT0_s);
    __syncthreads();              // K/V^T of head 0 visible

    #pragma unroll
    for (int h = 0; h < 3; ++h) {
        u16* qkb = (h & 1) ? qk1_s : qk0_s;
        u16* vtb = (h & 1) ? vT1_s : vT0_s;

        // pipeline: produce next head's K/V^T while consuming current
        if (h < 2) GEMM1(h + 1, (h & 1) ? qk0_s : qk1_s, (h & 1) ? vT0_s : vT1_s);

        // ---- GEMM2: S^T = K @ Q^T ----
        bf16x8 bq = ld8(qkb, myrow, lg * 8);
        f32x4 S[4];
        #pragma unroll
        for (int jt = 0; jt < 4; ++jt) {
            f32x4 z = {0.f, 0.f, 0.f, 0.f};
            S[jt] = mfma16(ld8(qkb, jt * 16 + lr, 32 + lg * 8), bq, z);
        }

        // ---- softmax via exp2 (scale/bias pre-folded into table) ----
        float ssum = 0.f;
        float e0[4], e1[4], e2[4], e3[4];
        #pragma unroll
        for (int reg = 0; reg < 4; ++reg) {
            e0[reg] = exp2f(fmaf(S[0][reg], SCALE2, bias0[reg])); ssum += e0[reg];
            e1[reg] = exp2f(fmaf(S[1][reg], SCALE2, bias1[reg])); ssum += e1[reg];
            e2[reg] = exp2f(fmaf(S[2][reg], SCALE2, bias2[reg])); ssum += e2[reg];
            e3[reg] = exp2f(fmaf(S[3][reg], SCALE2, bias3[reg])); ssum += e3[reg];
        }
        ssum = red_sum_16_32(ssum);
        float inv = 1.f / ssum;
        st4(p_s, myrow,      lg * 4, pack4(e0[0], e0[1], e0[2], e0[3]));
        st4(p_s, myrow, 16 + lg * 4, pack4(e1[0], e1[1], e1[2], e1[3]));
        st4(p_s, myrow, 32 + lg * 4, pack4(e2[0], e2[1], e2[2], e2[3]));
        st4(p_s, myrow, 48 + lg * 4, pack4(e3[0], e3[1], e3[2], e3[3]));

        // ---- GEMM3: O^T = V^T @ P^T (deferred normalization by inv) ----
        bf16x8 bp0 = ld8(p_s, myrow, lg * 8);
        bf16x8 bp1 = ld8(p_s, myrow, 32 + lg * 8);
        #pragma unroll
        for (int mt = 0; mt < 2; ++mt) {
            f32x4 c = {0.f, 0.f, 0.f, 0.f};
            c = mfma16(ld8(vtb, mt * 16 + lr,  0 + lg * 8), bp0, c);
            c = mfma16(ld8(vtb, mt * 16 + lr, 32 + lg * 8), bp1, c);
            // O -> own-row Q cols of qkb (Q only ever read own-row; done above)
            st4(qkb, myrow, mt * 16 + lg * 4,
                pack4(c[0] * inv, c[1] * inv, c[2] * inv, c[3] * inv));
        }

        // ---- GEMM4: proj += O @ Wout_h ----
        bf16x8 ao = ld8(qkb, myrow, lg * 8);
        #pragma unroll
        for (int nt = 0; nt < 6; ++nt)
            proj[nt] = mfma16(ao, ldfrag(wso_l + (size_t)(h * 6 + nt) * 512),
                              proj[nt]);

        if (h < 2) __syncthreads();   // next head's K/V^T ready; bufs swap safe
    }

    // ---- epilogue: +b_out, write out (rolled back), fused col sum/max ----
    float bo[6];
    #pragma unroll
    for (int nt = 0; nt < 6; ++nt) bo[nt] = b_out[nt * 16 + lr];
    float csum[6], cmax[6];
    #pragma unroll
    for (int nt = 0; nt < 6; ++nt) { csum[nt] = 0.f; cmax[nt] = -1e30f; }
    const int tok0 = 16 * w + lg * 4;
    const int r0t = tok0 / 7, c0t = tok0 - r0t * 7;
    #pragma unroll
    for (int reg = 0; reg < 4; ++reg) {
        if (tok0 + reg < 49) {
            int rr = r0t, cc = c0t + reg;
            if (cc >= 7) { cc -= 7; rr += 1; }
            int sr = wh * 7 + rr + 3;  if (sr >= 224) sr -= 224;
            int sc = ww * 7 + cc + 3;  if (sc >= 224) sc -= 224;
            size_t o0 = (((size_t)b * 224 + sr) * 224 + sc) * 96 + lr;
            #pragma unroll
            for (int nt = 0; nt < 6; ++nt) {
                float v = proj[nt][reg] + bo[nt];
                if (write_bf16) outw[o0 + nt * 16] = f2b(v);
                else            outf[o0 + nt * 16] = v;
                csum[nt] += v;
                cmax[nt] = fmaxf(cmax[nt], v);
            }
        }
    }
    #pragma unroll
    for (int nt = 0; nt < 6; ++nt) {
        csum[nt] = red_sum_16_32(csum[nt]);
        cmax[nt] = red_max_16_32(cmax[nt]);
    }
    // rsum/rmax reuse p_s; wait until all waves done with P/O reads.
    float* rsum = (float*)p_s;          // 384 floats
    float* rmax = rsum + 384;           // 384 floats
    __syncthreads();
    if (lg == 0) {
        #pragma unroll
        for (int nt = 0; nt < 6; ++nt) {
            rsum[w * 96 + nt * 16 + lr] = csum[nt];
            rmax[w * 96 + nt * 16 + lr] = cmax[nt];
        }
    }
    __syncthreads();
    if (tid < 96) {
        size_t o = ((size_t)b * 1024 + win) * 96 + tid;
        psum_win[o] = rsum[tid] + rsum[96 + tid] + rsum[192 + tid] + rsum[288 + tid];
        pmax_win[o] = fmaxf(fmaxf(rmax[tid], rmax[96 + tid]),
                            fmaxf(rmax[192 + tid], rmax[288 + tid]));
    }
}

// ============================================================================
// Gate: reduce 1024 per-window partials -> avg/max -> two MLPs -> sigmoid.
// ============================================================================
__global__ __launch_bounds__(384) void gate_kernel(
    const float* __restrict__ psum, const float* __restrict__ pmax,
    const float* __restrict__ w11, const float* __restrict__ b11,
    const float* __restrict__ w12, const float* __restrict__ b12,
    const float* __restrict__ w21, const float* __restrict__ b21,
    const float* __restrict__ w22, const float* __restrict__ b22,
    float* __restrict__ gate)
{
    const int b = blockIdx.x;
    const int tid = threadIdx.x;
    const int c = tid % 96, sub = tid / 96;
    __shared__ float ls[384], lm[384];
    __shared__ float avg[96], mx[96], h1[96], h2[96];

    float s = 0.f, m = -1e30f;
    for (int k = sub * 256; k < sub * 256 + 256; ++k) {
        size_t o = ((size_t)b * 1024 + k) * 96 + c;
        s += psum[o];
        m = fmaxf(m, pmax[o]);
    }
    ls[tid] = s; lm[tid] = m;
    __syncthreads();
    if (tid < 96) {
        s = ls[c] + ls[96 + c] + ls[192 + c] + ls[288 + c];
        m = fmaxf(fmaxf(lm[c], lm[96 + c]), fmaxf(lm[192 + c], lm[288 + c]));
        avg[c] = s * (1.0f / 50176.0f);
        mx[c]  = m;
    }
    __syncthreads();
    if (tid < 96) {
        float sa = b11[c], sm = b21[c];
        for (int ic = 0; ic < 96; ++ic) {
            sa = fmaf(avg[ic], w11[ic * 96 + c], sa);
            sm = fmaf(mx[ic],  w21[ic * 96 + c], sm);
        }
        h1[c] = fmaxf(sa, 0.f);
        h2[c] = fmaxf(sm, 0.f);
    }
    __syncthreads();
    if (tid < 96) {
        float a = b12[c], m2 = b22[c];
        for (int hh = 0; hh < 96; ++hh) {
            a  = fmaf(h1[hh], w12[hh * 96 + c], a);
            m2 = fmaf(h2[hh], w22[hh * 96 + c], m2);
        }
        float g = a + m2;
        gate[b * 96 + c] = 1.0f / (1.0f + __expf(-g));
    }
}

// ============================================================================
// Final scale: out_f32 = bf16_ws * gate
// ============================================================================
__global__ __launch_bounds__(256) void scale_bf16_kernel(
    const u16* __restrict__ outw, float* __restrict__ out,
    const float* __restrict__ gate)
{
    const size_t total8 = 38535168u / 8;
    for (size_t i8 = (size_t)blockIdx.x * blockDim.x + threadIdx.x; i8 < total8;
         i8 += (size_t)gridDim.x * blockDim.x) {
        size_t base = i8 * 8;
        int c = (int)(base % 96);
        int b = (int)(base / ((size_t)50176 * 96));
        u64 pk0 = *(const u64*)(outw + base);
        u64 pk1 = *(const u64*)(outw + base + 4);
        float4 g0 = *(const float4*)(gate + b * 96 + c);
        float4 g1 = *(const float4*)(gate + b * 96 + c + 4);
        float4 o0, o1;
        o0.x = bu2f((u16)(pk0      )) * g0.x;
        o0.y = bu2f((u16)(pk0 >> 16)) * g0.y;
        o0.z = bu2f((u16)(pk0 >> 32)) * g0.z;
        o0.w = bu2f((u16)(pk0 >> 48)) * g0.w;
        o1.x = bu2f((u16)(pk1      )) * g1.x;
        o1.y = bu2f((u16)(pk1 >> 16)) * g1.y;
        o1.z = bu2f((u16)(pk1 >> 32)) * g1.z;
        o1.w = bu2f((u16)(pk1 >> 48)) * g1.w;
        *(float4*)(out + base)     = o0;
        *(float4*)(out + base + 4) = o1;
    }
}

// f32 in-place fallback
__global__ __launch_bounds__(256) void scale_f32_kernel(
    float* __restrict__ out, const float* __restrict__ gate)
{
    const size_t total4 = 38535168u / 4;
    for (size_t i4 = (size_t)blockIdx.x * blockDim.x + threadIdx.x; i4 < total4;
         i4 += (size_t)gridDim.x * blockDim.x) {
        size_t base = i4 * 4;
        int c = (int)(base % 96);
        int b = (int)(base / ((size_t)50176 * 96));
        float4 u = ((const float4*)out)[i4];
        float4 g = *(const float4*)(gate + b * 96 + c);
        float4 o;
        o.x = u.x * g.x; o.y = u.y * g.y; o.z = u.z * g.z; o.w = u.w * g.w;
        ((float4*)out)[i4] = o;
    }
}

extern "C" void kernel_launch(void* const* d_in, const int* in_sizes, int n_in,
                              void* d_out, int out_size, void* d_ws, size_t ws_size,
                              hipStream_t stream) {
    const float* x     = (const float*)d_in[0];
    const float* wqkv  = (const float*)d_in[1];
    const float* pos   = (const float*)d_in[2];
    const float* wout  = (const float*)d_in[3];
    const float* bout  = (const float*)d_in[4];
    const float* m1w1  = (const float*)d_in[5];
    const float* m1b1  = (const float*)d_in[6];
    const float* m1w2  = (const float*)d_in[7];
    const float* m1b2  = (const float*)d_in[8];
    const float* m2w1  = (const float*)d_in[9];
    const float* m2b1  = (const float*)d_in[10];
    const float* m2w2  = (const float*)d_in[11];
    const float* m2b2  = (const float*)d_in[12];
    float* out = (float*)d_out;

    float* psum_win = (float*)d_ws;             // 3.15 MB
    float* pmax_win = psum_win + 8 * 1024 * 96; // 3.15 MB
    float* gatep    = pmax_win + 8 * 1024 * 96; // 3 KB
    u16*   wsq      = (u16*)(gatep + 8 * 96);   // 55 KB
    u16*   wso      = wsq + 27648;              // 18 KB
    float* biasT    = (float*)(wso + 9216);     // 64 KB (lane-contiguous layout)
    u16*   outw     = (u16*)(biasT + 16384);    // 77.1 MB (bf16 intermediate)

    const size_t base_bytes = (size_t)((char*)outw - (char*)d_ws);
    const size_t outw_bytes = (size_t)8 * 50176 * 96 * sizeof(u16);
    const int use_bf16 = (ws_size >= base_bytes + outw_bytes) ? 1 : 0;

    hipLaunchKernelGGL(prep_weights, dim3(108), dim3(256), 0, stream,
                       wqkv, wout, wsq, wso);
    hipLaunchKernelGGL(prep_bias, dim3(64), dim3(256), 0, stream,
                       pos, biasT);
    hipLaunchKernelGGL(swin_attn_mfma, dim3(8192), dim3(256), 0, stream,
                       x, biasT, wsq, wso, bout,
                       use_bf16 ? nullptr : out, use_bf16 ? outw : nullptr,
                       psum_win, pmax_win, use_bf16);
    hipLaunchKernelGGL(gate_kernel, dim3(8), dim3(384), 0, stream,
                       psum_win, pmax_win, m1w1, m1b1, m1w2, m1b2,
                       m2w1, m2b1, m2w2, m2b2, gatep);
    if (use_bf16) {
        hipLaunchKernelGGL(scale_bf16_kernel, dim3(2048), dim3(256), 0, stream,
                           outw, out, gatep);
    } else {
        hipLaunchKernelGGL(scale_f32_kernel, dim3(2048), dim3(256), 0, stream,
                           out, gatep);
    }
}